// Round 12
// baseline (87.831 us; speedup 1.0000x reference)
//
#include <hip/hip_runtime.h>
#include <math.h>

#define NB   8
#define NMEL 80
#define NTXT 512
#define NATT 80
#define NT1  1000
#define NT2  256
#define FTEMP 0.0005f

typedef __bf16 bf16x8 __attribute__((ext_vector_type(8)));
typedef float  f32x4  __attribute__((ext_vector_type(4)));

__device__ __forceinline__ unsigned short f2bf(float f) {
    unsigned u = __float_as_uint(f);
    unsigned r = (u + 0x7FFFu + ((u >> 16) & 1u)) >> 16;
    return (unsigned short)r;
}

__device__ __forceinline__ void gload_lds16(const void* g, void* l) {
    __builtin_amdgcn_global_load_lds(
        (const __attribute__((address_space(1))) void*)g,
        (__attribute__((address_space(3))) void*)l, 16, 0, 0);
}

struct KParams {
    const float *queries, *keys, *prior, *spk, *emo;
    const float *kw1, *kb1, *kw2, *kb2;
    const float *qw1, *qb1, *qw2, *qb2, *qw3, *qb3;
    const float *spk_kw, *spk_kb, *spk_qw, *spk_qb;
    const float *emo_kw, *emo_kb, *emo_qw, *emo_qb;
    const void* mask;
    float *q2, *kenc, *qenc;
    int* lens;
    unsigned short *Bt1, *Btq, *Abf1, *Abf2, *A1q, *A2q, *A3q;
    float *pqb1, *pqb2;
    float *out_attn, *out_lp;
};

// K1 partition: [0..1023] grid-strided zero+casts | [1024..1407] im2col | [1408] lens
#define PW_TOTAL (1024*1536 + 128*1024 + 256*256 + 128*256 + 128*128 + 256 + 128)
#define ZITEMS   (NB * NATT * NT2 / 4)     // 40960 f32x4
#define CAST_B   1024
#define K1_IM    CAST_B
#define K1_LENS  (K1_IM + 384)
#define K1_GRID  (K1_LENS + 1)

// ---------------------------------------------------------------------------
// K1: grid-strided {kenc zero, weight casts} | im2col with inline ILP-4 shifts
//     and COALESCED ushort4 Bt writes | lens
__global__ __launch_bounds__(256)
void prep_im2col(KParams p) {
    __shared__ float xs[80 * 67];
    __shared__ float sh[80];
    int bx = blockIdx.x, tid = threadIdx.x;
    int lane = tid & 63, wv = tid >> 6;

    if (bx < CAST_B) {
        const int n0c = 1024 * 1536, n1c = 128 * 1024, n2c = 256 * 256,
                  n3c = 128 * 256, n4c = 128 * 128;
        const int TOT = ZITEMS + PW_TOTAL;
        for (int ii = bx * 256 + tid; ii < TOT; ii += CAST_B * 256) {
            int i = ii;
            if (i < ZITEMS) { f32x4 z = {}; ((f32x4*)p.kenc)[i] = z; continue; }
            i -= ZITEMS;
            if (i < n0c) { p.Abf1[i] = f2bf(p.kw1[i]); continue; }
            i -= n0c;
            if (i < n1c) { int oc = i >> 10;
                p.Abf2[i] = (oc < 80) ? f2bf(p.kw2[i]) : (unsigned short)0; continue; }
            i -= n1c;
            if (i < n2c) { int m = i >> 8, c = i & 255;
                p.A1q[i] = (m < 160 && c < 240) ? f2bf(p.qw1[m * 240 + c]) : (unsigned short)0; continue; }
            i -= n2c;
            if (i < n3c) { int m = i >> 8, c = i & 255;
                p.A2q[i] = (m < 80 && c < 160) ? f2bf(p.qw2[m * 160 + c]) : (unsigned short)0; continue; }
            i -= n3c;
            if (i < n4c) { int m = i >> 7, c = i & 127;
                p.A3q[i] = (m < 80 && c < 80) ? f2bf(p.qw3[m * 80 + c]) : (unsigned short)0; continue; }
            i -= n4c;
            if (i < 256) { p.pqb1[i] = (i < 160) ? p.qb1[i] : 0.f; continue; }
            i -= 256;
            p.pqb2[i] = (i < 80) ? p.qb2[i] : 0.f;
        }
        return;
    }
    if (bx < K1_LENS) {
        int u = bx - K1_IM;
        if (u < 256) {
            // ---- keys im2col, shifts recomputed with ILP-4 ----
            int x = u & 3, b = (u >> 2) & 7, z = u >> 5;
            int t0 = x * 64, ci0 = z * 64;
            const float* e1 = p.spk + (size_t)b * NTXT;
            const float* e2 = p.emo + (size_t)b * NTXT;
            #pragma unroll
            for (int g = 0; g < 4; ++g) {
                int cl = wv * 16 + g * 4;
                const float* w1b = p.spk_kw + (size_t)(ci0 + cl) * NTXT;
                const float* w2b = p.emo_kw + (size_t)(ci0 + cl) * NTXT;
                float s0 = 0.f, s1 = 0.f, s2 = 0.f, s3 = 0.f;
                #pragma unroll
                for (int st = 0; st < 8; ++st) {
                    int j = st * 64 + lane;
                    float ev1 = e1[j], ev2 = e2[j];
                    s0 += ev1 * w1b[j]            + ev2 * w2b[j];
                    s1 += ev1 * w1b[j + NTXT]     + ev2 * w2b[j + NTXT];
                    s2 += ev1 * w1b[j + 2 * NTXT] + ev2 * w2b[j + 2 * NTXT];
                    s3 += ev1 * w1b[j + 3 * NTXT] + ev2 * w2b[j + 3 * NTXT];
                }
                #pragma unroll
                for (int off = 32; off > 0; off >>= 1) {
                    s0 += __shfl_down(s0, off); s1 += __shfl_down(s1, off);
                    s2 += __shfl_down(s2, off); s3 += __shfl_down(s3, off);
                }
                if (lane == 0) {
                    int c = ci0 + cl;
                    sh[cl]     = s0 + p.spk_kb[c]     + p.emo_kb[c];
                    sh[cl + 1] = s1 + p.spk_kb[c + 1] + p.emo_kb[c + 1];
                    sh[cl + 2] = s2 + p.spk_kb[c + 2] + p.emo_kb[c + 2];
                    sh[cl + 3] = s3 + p.spk_kb[c + 3] + p.emo_kb[c + 3];
                }
            }
            __syncthreads();
            for (int i = tid; i < 64 * 66; i += 256) {
                int cis = i / 66, tt = i % 66;
                int tg = t0 + tt - 1;
                float v = 0.f;
                if (tg >= 0 && tg < NT2)
                    v = p.keys[((size_t)(b * NTXT + ci0 + cis)) * NT2 + tg] + sh[cis];
                xs[cis * 67 + tt] = v;
            }
            __syncthreads();
            // coalesced: each row t is a contiguous 192-ushort span at ci0*3
            for (int i = tid; i < 64 * 48; i += 256) {
                int t = i / 48, m = i - t * 48;
                int e0 = m * 4;
                unsigned short pk[4];
                #pragma unroll
                for (int jj = 0; jj < 4; ++jj) {
                    int e = e0 + jj;
                    int cis = e / 3, k = e - cis * 3;
                    pk[jj] = f2bf(xs[cis * 67 + t + k]);
                }
                *(ushort4*)(p.Bt1 + ((size_t)(b * NT2 + t0 + t)) * 1536 + (size_t)ci0 * 3 + e0) =
                    make_ushort4(pk[0], pk[1], pk[2], pk[3]);
            }
            return;
        }
        // ---- queries im2col, shifts recomputed with ILP-4 (80 ch: 5 groups/wave) ----
        int qb = u - 256;
        int x = qb & 15, b = qb >> 4;
        int t0 = x * 64;
        const float* e1 = p.spk + (size_t)b * NTXT;
        const float* e2 = p.emo + (size_t)b * NTXT;
        #pragma unroll
        for (int g = 0; g < 5; ++g) {
            int cl = wv * 20 + g * 4;
            const float* w1b = p.spk_qw + (size_t)cl * NTXT;
            const float* w2b = p.emo_qw + (size_t)cl * NTXT;
            float s0 = 0.f, s1 = 0.f, s2 = 0.f, s3 = 0.f;
            #pragma unroll
            for (int st = 0; st < 8; ++st) {
                int j = st * 64 + lane;
                float ev1 = e1[j], ev2 = e2[j];
                s0 += ev1 * w1b[j]            + ev2 * w2b[j];
                s1 += ev1 * w1b[j + NTXT]     + ev2 * w2b[j + NTXT];
                s2 += ev1 * w1b[j + 2 * NTXT] + ev2 * w2b[j + 2 * NTXT];
                s3 += ev1 * w1b[j + 3 * NTXT] + ev2 * w2b[j + 3 * NTXT];
            }
            #pragma unroll
            for (int off = 32; off > 0; off >>= 1) {
                s0 += __shfl_down(s0, off); s1 += __shfl_down(s1, off);
                s2 += __shfl_down(s2, off); s3 += __shfl_down(s3, off);
            }
            if (lane == 0) {
                sh[cl]     = s0 + p.spk_qb[cl]     + p.emo_qb[cl];
                sh[cl + 1] = s1 + p.spk_qb[cl + 1] + p.emo_qb[cl + 1];
                sh[cl + 2] = s2 + p.spk_qb[cl + 2] + p.emo_qb[cl + 2];
                sh[cl + 3] = s3 + p.spk_qb[cl + 3] + p.emo_qb[cl + 3];
            }
        }
        __syncthreads();
        for (int i = tid; i < 80 * 66; i += 256) {
            int cis = i / 66, tt = i % 66;
            int tg = t0 + tt - 1;
            float v = 0.f;
            if (tg >= 0 && tg < NT1)
                v = p.queries[((size_t)(b * NMEL + cis)) * NT1 + tg] + sh[cis];
            xs[cis * 67 + tt] = v;
        }
        __syncthreads();
        // coalesced: row = 256 ushorts (240 real + 16 zero pad)
        for (int i = tid; i < 64 * 64; i += 256) {
            int t = i >> 6, m = i & 63;
            int tg = t0 + t;
            if (tg >= NT1) continue;
            int e0 = m * 4;
            unsigned short pk[4];
            #pragma unroll
            for (int jj = 0; jj < 4; ++jj) {
                int e = e0 + jj;
                unsigned short v = 0;
                if (e < 240) { int cis = e / 3, k = e - cis * 3; v = f2bf(xs[cis * 67 + t + k]); }
                pk[jj] = v;
            }
            *(ushort4*)(p.Btq + ((size_t)(b * NT1 + tg)) * 256 + e0) =
                make_ushort4(pk[0], pk[1], pk[2], pk[3]);
        }
        return;
    }
    // lens: one block, first wave
    if (tid >= 64) return;
    {
        const int* mi = (const int*)p.mask;
        int bf16p = 0, f16p = 0, f32m = 0, big = 0, one = 0;
        for (int i = tid; i < 512; i += 64) {
            unsigned v = (unsigned)mi[i];
            bf16p |= (v == 0x3F803F80u);
            f16p  |= (v == 0x3C003C00u) || (v == 0x3C000000u);
            f32m  |= (v == 0x3F800000u);
            big   |= (v > 1u);
            one   |= (v == 1u);
        }
        bf16p = __any(bf16p); f16p = __any(f16p); f32m = __any(f32m);
        big = __any(big); one = __any(one);
        int mode;
        if (bf16p)      mode = 3;
        else if (f16p)  mode = 4;
        else if (f32m)  mode = 2;
        else if (big)   mode = 0;
        else if (one)   mode = 1;
        else            mode = 5;
        for (int b = 0; b < NB; ++b) {
            int cnt = 0;
            for (int t = tid; t < NT2; t += 64) {
                bool m;
                switch (mode) {
                    case 0: m = ((const unsigned char*)p.mask)[b*NT2 + t] != 0; break;
                    case 1: m = ((const int*)p.mask)[b*NT2 + t] != 0; break;
                    case 2: m = ((const float*)p.mask)[b*NT2 + t] != 0.f; break;
                    case 3: case 4: m = ((const unsigned short*)p.mask)[b*NT2 + t] != 0; break;
                    default: m = false; break;
                }
                cnt += m ? 0 : 1;
            }
            for (int off = 32; off > 0; off >>= 1) cnt += __shfl_down(cnt, off);
            if (tid == 0) p.lens[b] = cnt;
        }
    }
}

// ---------------------------------------------------------------------------
// K2: blocks 0..255 keys conv1 (128x64, dbuf, XCD-local (y,x) remap) + mini
//     conv2 (atomicAdd); blocks 256..380 query chain (dbuf conv2/conv3 A).
__global__ __launch_bounds__(256)
void gemm_fused(KParams p) {
    __shared__ __attribute__((aligned(16))) char smem[74240];
    int tid = threadIdx.x, bx = blockIdx.x;
    int lane = tid & 63, wv = tid >> 6;
    int wr = wv >> 1, wc = wv & 1;
    int srow = lane >> 3;
    int selem = (((lane & 7) * 16) ^ ((srow & 7) << 4)) >> 1;

    if (bx < 256) {
        // XCD-locality remap: XCD j (bx%8) gets x in {4j..4j+3}, all 8 y.
        // Per-XCD L2 working set: full A (3MB) + 4 B-panels (0.77MB) < 4MB.
        int j = bx & 7, i = bx >> 3;
        int x = j * 4 + (i & 3);
        int y = i >> 2;
        // layout: As0 [0,16K) As1 [16K,32K) Bs0 [32K,40K) Bs1 [40K,48K) B2c [48K,64K)
        unsigned short* B2c = (unsigned short*)(smem + 49152);
        int m0 = y * 128, n0 = x * 64;
        f32x4 acc[4][2] = {};

        {   // prologue: stage K-step 0 into buffer 0
            #pragma unroll
            for (int i2 = 0; i2 < 4; ++i2) {
                int ch = wv * 4 + i2;
                gload_lds16(p.Abf1 + (size_t)(m0 + ch * 8 + srow) * 1536 + selem, smem + ch * 1024);
            }
            #pragma unroll
            for (int i2 = 0; i2 < 2; ++i2) {
                int ch = wv * 2 + i2;
                gload_lds16(p.Bt1 + (size_t)(n0 + ch * 8 + srow) * 1536 + selem, smem + 32768 + ch * 1024);
            }
        }
        __syncthreads();
        int cur = 0;
        for (int t = 0; t < 24; ++t) {
            if (t < 23) {
                int k0n = (t + 1) * 64;
                char* an = smem + (cur ^ 1) * 16384;
                char* bn = smem + 32768 + (cur ^ 1) * 8192;
                #pragma unroll
                for (int i2 = 0; i2 < 4; ++i2) {
                    int ch = wv * 4 + i2;
                    gload_lds16(p.Abf1 + (size_t)(m0 + ch * 8 + srow) * 1536 + k0n + selem, an + ch * 1024);
                }
                #pragma unroll
                for (int i2 = 0; i2 < 2; ++i2) {
                    int ch = wv * 2 + i2;
                    gload_lds16(p.Bt1 + (size_t)(n0 + ch * 8 + srow) * 1536 + k0n + selem, bn + ch * 1024);
                }
            }
            const char* Ab = smem + cur * 16384;
            const char* Bb = smem + 32768 + cur * 8192;
            #pragma unroll
            for (int ks = 0; ks < 2; ++ks) {
                bf16x8 af[4], bfr[2];
                int kb = ks * 64 + (lane >> 4) * 16;
                #pragma unroll
                for (int mi = 0; mi < 4; ++mi) {
                    int row = wr * 64 + mi * 16 + (lane & 15);
                    af[mi] = *(const bf16x8*)(Ab + row * 128 + (kb ^ ((row & 7) << 4)));
                }
                #pragma unroll
                for (int ni = 0; ni < 2; ++ni) {
                    int row = wc * 32 + ni * 16 + (lane & 15);
                    bfr[ni] = *(const bf16x8*)(Bb + row * 128 + (kb ^ ((row & 7) << 4)));
                }
                #pragma unroll
                for (int mi = 0; mi < 4; ++mi)
                    #pragma unroll
                    for (int ni = 0; ni < 2; ++ni)
                        acc[mi][ni] = __builtin_amdgcn_mfma_f32_16x16x32_bf16(af[mi], bfr[ni], acc[mi][ni], 0, 0, 0);
            }
            __syncthreads();
            cur ^= 1;
        }
        // epilogue: relu(acc+kb1) -> bf16 LDS B2c [col][local_ch 0..127], swizzled
        #pragma unroll
        for (int mi = 0; mi < 4; ++mi) {
            #pragma unroll
            for (int ni = 0; ni < 2; ++ni) {
                int mb = wr * 64 + mi * 16 + (lane >> 4) * 4;
                int row = wc * 32 + ni * 16 + (lane & 15);
                unsigned short pk[4];
                #pragma unroll
                for (int jj = 0; jj < 4; ++jj) {
                    float v = acc[mi][ni][jj] + p.kb1[m0 + mb + jj];
                    pk[jj] = f2bf(fmaxf(v, 0.f));
                }
                int bo = mb * 2;
                int addr = row * 256 + ((bo & ~15) ^ ((row & 7) << 4)) + (bo & 15);
                *(ushort4*)((char*)B2c + addr) = make_ushort4(pk[0], pk[1], pk[2], pk[3]);
            }
        }
        // mini conv2 (2-deep A prefetch)
        #pragma unroll
        for (int i2 = 0; i2 < 4; ++i2) {
            int ch = wv * 4 + i2;
            gload_lds16(p.Abf2 + (size_t)(ch * 8 + srow) * 1024 + y * 128 + selem, smem + ch * 1024);
        }
        __syncthreads();   // A2(k0=0) loaded AND B2c writes complete
        #pragma unroll
        for (int i2 = 0; i2 < 4; ++i2) {
            int ch = wv * 4 + i2;
            gload_lds16(p.Abf2 + (size_t)(ch * 8 + srow) * 1024 + y * 128 + 64 + selem, smem + 16384 + ch * 1024);
        }
        f32x4 acc2[4][2] = {};
        #pragma unroll
        for (int k0 = 0; k0 < 128; k0 += 64) {
            const char* Ab = smem + (k0 >> 6) * 16384;
            #pragma unroll
            for (int ks = 0; ks < 2; ++ks) {
                bf16x8 af[4], bfr[2];
                int kb = ks * 64 + (lane >> 4) * 16;
                #pragma unroll
                for (int mi = 0; mi < 4; ++mi) {
                    int row = wr * 64 + mi * 16 + (lane & 15);
                    af[mi] = *(const bf16x8*)(Ab + row * 128 + (kb ^ ((row & 7) << 4)));
                }
                #pragma unroll
                for (int ni = 0; ni < 2; ++ni) {
                    int row = wc * 32 + ni * 16 + (lane & 15);
                    int kbyte = k0 * 2 + kb;
                    bfr[ni] = *(const bf16x8*)((const char*)B2c + row * 256 + (kbyte ^ ((row & 7) << 4)));
                }
                #pragma unroll
                for (int mi = 0; mi < 4; ++mi)
                    #pragma unroll
                    for (int ni = 0; ni < 2; ++ni)
                        acc2[mi][ni] = __builtin_amdgcn_mfma_f32_16x16x32_bf16(af[mi], bfr[ni], acc2[mi][ni], 0, 0, 0);
            }
            if (k0 == 0) __syncthreads();
        }
        #pragma unroll
        for (int mi = 0; mi < 4; ++mi) {
            #pragma unroll
            for (int ni = 0; ni < 2; ++ni) {
                int mb = wr * 64 + mi * 16 + (lane >> 4) * 4;
                int n  = n0 + wc * 32 + ni * 16 + (lane & 15);
                int b = n >> 8, t = n & 255;
                #pragma unroll
                for (int jj = 0; jj < 4; ++jj) {
                    int m = mb + jj;
                    if (m < NATT) {
                        float v = acc2[mi][ni][jj] + ((y == 0) ? p.kb2[m] : 0.f);
                        atomicAdd(&p.kenc[((size_t)(b * NATT + m)) * NT2 + t], v);
                    }
                }
            }
        }
    } else {
        // ---- fused query chain ----
        unsigned short* As = (unsigned short*)smem;            // [128][64]
        unsigned short* Bs = (unsigned short*)(smem + 16384);  // [64][64]
        unsigned short* B2 = (unsigned short*)(smem + 24576);  // [64][256]
        unsigned short* B3 = (unsigned short*)(smem + 57344);  // [64][128]
        float* red = (float*)(smem + 73728);                   // [128]
        int n0 = (bx - 256) * 64;
        // conv1 (M=256 in 2 chunks, K=256), B from global Btq (single-buffered)
        #pragma unroll
        for (int mc = 0; mc < 2; ++mc) {
            int m0 = mc * 128;
            f32x4 acc[4][2] = {};
            for (int k0 = 0; k0 < 256; k0 += 64) {
                #pragma unroll
                for (int i2 = 0; i2 < 4; ++i2) {
                    int ch = wv * 4 + i2;
                    gload_lds16(p.A1q + (size_t)(m0 + ch * 8 + srow) * 256 + k0 + selem, (char*)As + ch * 1024);
                }
                #pragma unroll
                for (int i2 = 0; i2 < 2; ++i2) {
                    int ch = wv * 2 + i2;
                    gload_lds16(p.Btq + (size_t)(n0 + ch * 8 + srow) * 256 + k0 + selem, (char*)Bs + ch * 1024);
                }
                __syncthreads();
                #pragma unroll
                for (int ks = 0; ks < 2; ++ks) {
                    bf16x8 af[4], bfr[2];
                    int kb = ks * 64 + (lane >> 4) * 16;
                    #pragma unroll
                    for (int mi = 0; mi < 4; ++mi) {
                        int row = wr * 64 + mi * 16 + (lane & 15);
                        af[mi] = *(const bf16x8*)((const char*)As + row * 128 + (kb ^ ((row & 7) << 4)));
                    }
                    #pragma unroll
                    for (int ni = 0; ni < 2; ++ni) {
                        int row = wc * 32 + ni * 16 + (lane & 15);
                        bfr[ni] = *(const bf16x8*)((const char*)Bs + row * 128 + (kb ^ ((row & 7) << 4)));
                    }
                    #pragma unroll
                    for (int mi = 0; mi < 4; ++mi)
                        #pragma unroll
                        for (int ni = 0; ni < 2; ++ni)
                            acc[mi][ni] = __builtin_amdgcn_mfma_f32_16x16x32_bf16(af[mi], bfr[ni], acc[mi][ni], 0, 0, 0);
                }
                __syncthreads();
            }
            #pragma unroll
            for (int mi = 0; mi < 4; ++mi) {
                #pragma unroll
                for (int ni = 0; ni < 2; ++ni) {
                    int mb = m0 + wr * 64 + mi * 16 + (lane >> 4) * 4;
                    int row = wc * 32 + ni * 16 + (lane & 15);
                    unsigned short pk[4];
                    #pragma unroll
                    for (int jj = 0; jj < 4; ++jj) {
                        float v = acc[mi][ni][jj] + p.pqb1[mb + jj];
                        pk[jj] = f2bf(fmaxf(v, 0.f));
                    }
                    int bo = mb * 2;
                    int addr = row * 512 + ((bo & ~15) ^ ((row & 7) << 4)) + (bo & 15);
                    *(ushort4*)((char*)B2 + addr) = make_ushort4(pk[0], pk[1], pk[2], pk[3]);
                }
            }
        }
        // conv2 (M=128, K=256), B in LDS B2; A double-buffered (As0 @0, As1 @B3 region)
        {
            char* Abuf[2] = { smem, smem + 57344 };
            #pragma unroll
            for (int i2 = 0; i2 < 4; ++i2) {
                int ch = wv * 4 + i2;
                gload_lds16(p.A2q + (size_t)(ch * 8 + srow) * 256 + selem, Abuf[0] + ch * 1024);
            }
            __syncthreads();   // As0 ready AND B2 writes complete
            f32x4 acc[4][2] = {};
            for (int t = 0; t < 4; ++t) {
                if (t < 3) {
                    int k0n = (t + 1) * 64;
                    char* an = Abuf[(t + 1) & 1];
                    #pragma unroll
                    for (int i2 = 0; i2 < 4; ++i2) {
                        int ch = wv * 4 + i2;
                        gload_lds16(p.A2q + (size_t)(ch * 8 + srow) * 256 + k0n + selem, an + ch * 1024);
                    }
                }
                const char* Ab = Abuf[t & 1];
                int k0 = t * 64;
                #pragma unroll
                for (int ks = 0; ks < 2; ++ks) {
                    bf16x8 af[4], bfr[2];
                    int kb = ks * 64 + (lane >> 4) * 16;
                    #pragma unroll
                    for (int mi = 0; mi < 4; ++mi) {
                        int row = wr * 64 + mi * 16 + (lane & 15);
                        af[mi] = *(const bf16x8*)(Ab + row * 128 + (kb ^ ((row & 7) << 4)));
                    }
                    #pragma unroll
                    for (int ni = 0; ni < 2; ++ni) {
                        int row = wc * 32 + ni * 16 + (lane & 15);
                        int kbyte = k0 * 2 + kb;
                        bfr[ni] = *(const bf16x8*)((const char*)B2 + row * 512 + (kbyte ^ ((row & 7) << 4)));
                    }
                    #pragma unroll
                    for (int mi = 0; mi < 4; ++mi)
                        #pragma unroll
                        for (int ni = 0; ni < 2; ++ni)
                            acc[mi][ni] = __builtin_amdgcn_mfma_f32_16x16x32_bf16(af[mi], bfr[ni], acc[mi][ni], 0, 0, 0);
                }
                __syncthreads();   // drains prefetch; readers of Ab done (incl. t=3 before B3 write)
            }
            #pragma unroll
            for (int mi = 0; mi < 4; ++mi) {
                #pragma unroll
                for (int ni = 0; ni < 2; ++ni) {
                    int mb = wr * 64 + mi * 16 + (lane >> 4) * 4;
                    int row = wc * 32 + ni * 16 + (lane & 15);
                    unsigned short pk[4];
                    #pragma unroll
                    for (int jj = 0; jj < 4; ++jj) {
                        float v = acc[mi][ni][jj] + p.pqb2[mb + jj];
                        pk[jj] = f2bf(fmaxf(v, 0.f));
                    }
                    int bo = mb * 2;
                    int addr = row * 256 + ((bo & ~15) ^ ((row & 7) << 4)) + (bo & 15);
                    *(ushort4*)((char*)B3 + addr) = make_ushort4(pk[0], pk[1], pk[2], pk[3]);
                }
            }
        }
        // conv3 (M=128, K=128), B in LDS B3; A dbuf (As0 @0, As1 @B2 region)
        {
            #pragma unroll
            for (int i2 = 0; i2 < 4; ++i2) {
                int ch = wv * 4 + i2;
                gload_lds16(p.A3q + (size_t)(ch * 8 + srow) * 128 + selem, smem + ch * 1024);
                gload_lds16(p.A3q + (size_t)(ch * 8 + srow) * 128 + 64 + selem, smem + 24576 + ch * 1024);
            }
            __syncthreads();   // both A stages ready AND B3 writes complete
            f32x4 acc[4][2] = {};
            #pragma unroll
            for (int k0 = 0; k0 < 128; k0 += 64) {
                const char* Ab = (k0 == 0) ? smem : smem + 24576;
                #pragma unroll
                for (int ks = 0; ks < 2; ++ks) {
                    bf16x8 af[4], bfr[2];
                    int kb = ks * 64 + (lane >> 4) * 16;
                    #pragma unroll
                    for (int mi = 0; mi < 4; ++mi) {
                        int row = wr * 64 + mi * 16 + (lane & 15);
                        af[mi] = *(const bf16x8*)(Ab + row * 128 + (kb ^ ((row & 7) << 4)));
                    }
                    #pragma unroll
                    for (int ni = 0; ni < 2; ++ni) {
                        int row = wc * 32 + ni * 16 + (lane & 15);
                        int kbyte = k0 * 2 + kb;
                        bfr[ni] = *(const bf16x8*)((const char*)B3 + row * 256 + (kbyte ^ ((row & 7) << 4)));
                    }
                    #pragma unroll
                    for (int mi = 0; mi < 4; ++mi)
                        #pragma unroll
                        for (int ni = 0; ni < 2; ++ni)
                            acc[mi][ni] = __builtin_amdgcn_mfma_f32_16x16x32_bf16(af[mi], bfr[ni], acc[mi][ni], 0, 0, 0);
                }
            }
            float part[2] = {0.f, 0.f};
            #pragma unroll
            for (int mi = 0; mi < 4; ++mi) {
                #pragma unroll
                for (int ni = 0; ni < 2; ++ni) {
                    int mb = wr * 64 + mi * 16 + (lane >> 4) * 4;
                    int n  = n0 + wc * 32 + ni * 16 + (lane & 15);
                    int b = n / NT1, t = n - b * NT1;
                    #pragma unroll
                    for (int jj = 0; jj < 4; ++jj) {
                        int m = mb + jj;
                        if (m < NATT) {
                            float v = acc[mi][ni][jj] + p.qb3[m];
                            part[ni] += v * v;
                            p.qenc[((size_t)(b * NATT + m)) * NT1 + t] = v;
                        }
                    }
                }
            }
            #pragma unroll
            for (int ni = 0; ni < 2; ++ni) {
                part[ni] += __shfl_xor(part[ni], 16);
                part[ni] += __shfl_xor(part[ni], 32);
            }
            if ((lane >> 4) == 0) {
                red[wr * 64 + wc * 32 + (lane & 15)]      = part[0];
                red[wr * 64 + wc * 32 + 16 + (lane & 15)] = part[1];
            }
            __syncthreads();
            if (tid < 64) p.q2[n0 + tid] = red[tid] + red[64 + tid];
        }
    }
}

// ---------------------------------------------------------------------------
// K3: attn, t-tile 16 (4 rows/wave), grid 504 = 63 tiles x 8 b. k2 inline.
__global__ __launch_bounds__(256)
void attn_kernel(KParams p) {
    __shared__ float kl[16 * 256];
    __shared__ float ql[16 * 16];
    int bx = blockIdx.x, tid = threadIdx.x;
    int lane = tid & 63, wv = tid >> 6;
    int b = bx / 63;
    int t0 = (bx - b * 63) * 16;
    int s0 = lane * 4;
    f32x4 acc[4] = {};
    f32x4 k2v = {};
    for (int ci0 = 0; ci0 < NATT; ci0 += 16) {
        for (int i = tid; i < 1024; i += 256) {
            int ci = i >> 6, sq = (i & 63) * 4;
            *(f32x4*)&kl[ci * 256 + sq] =
                *(const f32x4*)&p.kenc[((size_t)(b * NATT + ci0 + ci)) * NT2 + sq];
        }
        {
            int ci = tid >> 4, tt = tid & 15;
            int tg = t0 + tt;
            ql[ci * 16 + tt] = (tg < NT1) ? p.qenc[((size_t)(b * NATT + ci0 + ci)) * NT1 + tg] : 0.f;
        }
        __syncthreads();
        #pragma unroll
        for (int ci = 0; ci < 16; ++ci) {
            f32x4 kv = *(const f32x4*)&kl[ci * 256 + s0];
            #pragma unroll
            for (int jj = 0; jj < 4; ++jj) k2v[jj] += kv[jj] * kv[jj];
            f32x4 qa = *(const f32x4*)&ql[ci * 16 + wv * 4];
            #pragma unroll
            for (int r = 0; r < 4; ++r)
                #pragma unroll
                for (int jj = 0; jj < 4; ++jj) acc[r][jj] += qa[r] * kv[jj];
        }
        __syncthreads();
    }
    int len = p.lens[b];
    #pragma unroll
    for (int r = 0; r < 4; ++r) {
        int t = t0 + wv * 4 + r;
        if (t >= NT1) continue;
        float q2v = p.q2[b * NT1 + t];
        float lg[4];
        float mx = -INFINITY;
        #pragma unroll
        for (int jj = 0; jj < 4; ++jj) {
            lg[jj] = -FTEMP * (q2v + k2v[jj] - 2.f * acc[r][jj]);
            mx = fmaxf(mx, lg[jj]);
        }
        for (int off = 32; off > 0; off >>= 1) mx = fmaxf(mx, __shfl_xor(mx, off));
        float se = 0.f;
        #pragma unroll
        for (int jj = 0; jj < 4; ++jj) se += __expf(lg[jj] - mx);
        for (int off = 32; off > 0; off >>= 1) se += __shfl_xor(se, off);
        float logZ = mx + __logf(se);
        f32x4 prv = *(const f32x4*)&p.prior[((size_t)b * NT1 + t) * NT2 + s0];
        float lp[4];
        float mx2 = -INFINITY;
        #pragma unroll
        for (int jj = 0; jj < 4; ++jj) {
            lp[jj] = lg[jj] - logZ + __logf(prv[jj] + 1e-8f);
            if (s0 + jj < len) mx2 = fmaxf(mx2, lp[jj]);
        }
        for (int off = 32; off > 0; off >>= 1) mx2 = fmaxf(mx2, __shfl_xor(mx2, off));
        float se2 = 0.f;
        float ex[4];
        #pragma unroll
        for (int jj = 0; jj < 4; ++jj) {
            ex[jj] = (s0 + jj < len) ? __expf(lp[jj] - mx2) : 0.f;
            se2 += ex[jj];
        }
        for (int off = 32; off > 0; off >>= 1) se2 += __shfl_xor(se2, off);
        float inv = 1.f / se2;
        size_t o = ((size_t)b * NT1 + t) * NT2 + s0;
        f32x4 oa, ol;
        #pragma unroll
        for (int jj = 0; jj < 4; ++jj) { oa[jj] = ex[jj] * inv; ol[jj] = lp[jj]; }
        *(f32x4*)&p.out_attn[o] = oa;
        *(f32x4*)&p.out_lp[o]   = ol;
    }
}

// ---------------------------------------------------------------------------
extern "C" void kernel_launch(void* const* d_in, const int* in_sizes, int n_in,
                              void* d_out, int out_size, void* d_ws, size_t ws_size,
                              hipStream_t stream) {
    (void)in_sizes; (void)n_in; (void)out_size; (void)ws_size;
    KParams p;
    p.queries = (const float*)d_in[0];
    p.keys    = (const float*)d_in[1];
    p.prior   = (const float*)d_in[2];
    p.spk     = (const float*)d_in[3];
    p.emo     = (const float*)d_in[4];
    p.kw1     = (const float*)d_in[5];
    p.kb1     = (const float*)d_in[6];
    p.kw2     = (const float*)d_in[7];
    p.kb2     = (const float*)d_in[8];
    p.qw1     = (const float*)d_in[9];
    p.qb1     = (const float*)d_in[10];
    p.qw2     = (const float*)d_in[11];
    p.qb2     = (const float*)d_in[12];
    p.qw3     = (const float*)d_in[13];
    p.qb3     = (const float*)d_in[14];
    p.spk_kw  = (const float*)d_in[15];
    p.spk_kb  = (const float*)d_in[16];
    p.spk_qw  = (const float*)d_in[17];
    p.spk_qb  = (const float*)d_in[18];
    p.emo_kw  = (const float*)d_in[19];
    p.emo_kb  = (const float*)d_in[20];
    p.emo_qw  = (const float*)d_in[21];
    p.emo_qb  = (const float*)d_in[22];
    p.mask    = d_in[23];

    float* w = (float*)d_ws;
    size_t off = 0;
    p.lens   = (int*)(w + off); off += 16;
    p.q2     = w + off; off += NB * NT1;
    p.kenc   = w + off; off += (size_t)NB * NATT * NT2;
    p.qenc   = w + off; off += (size_t)NB * NATT * NT1;
    p.Bt1    = (unsigned short*)(w + off); off += (size_t)2048 * 1536 / 2;
    p.Btq    = (unsigned short*)(w + off); off += (size_t)8064 * 256 / 2;
    p.Abf1   = (unsigned short*)(w + off); off += (size_t)1024 * 1536 / 2;
    p.Abf2   = (unsigned short*)(w + off); off += (size_t)128 * 1024 / 2;
    p.A1q    = (unsigned short*)(w + off); off += (size_t)256 * 256 / 2;
    p.A2q    = (unsigned short*)(w + off); off += (size_t)128 * 256 / 2;
    p.A3q    = (unsigned short*)(w + off); off += (size_t)128 * 128 / 2;
    p.pqb1   = w + off; off += 256;
    p.pqb2   = w + off; off += 128;

    p.out_attn = (float*)d_out;
    p.out_lp   = p.out_attn + (size_t)NB * NT1 * NT2;

    prep_im2col<<<K1_GRID, 256, 0, stream>>>(p);
    gemm_fused<<<381, 256, 0, stream>>>(p);
    attn_kernel<<<504, 256, 0, stream>>>(p);
}

// Round 13
// 84.305 us; speedup vs baseline: 1.0418x; 1.0418x over previous
//
#include <hip/hip_runtime.h>
#include <math.h>

#define NB   8
#define NMEL 80
#define NTXT 512
#define NATT 80
#define NT1  1000
#define NT2  256
#define FTEMP 0.0005f

typedef __bf16 bf16x8 __attribute__((ext_vector_type(8)));
typedef float  f32x4  __attribute__((ext_vector_type(4)));

__device__ __forceinline__ unsigned short f2bf(float f) {
    unsigned u = __float_as_uint(f);
    unsigned r = (u + 0x7FFFu + ((u >> 16) & 1u)) >> 16;
    return (unsigned short)r;
}

__device__ __forceinline__ void gload_lds16(const void* g, void* l) {
    __builtin_amdgcn_global_load_lds(
        (const __attribute__((address_space(1))) void*)g,
        (__attribute__((address_space(3))) void*)l, 16, 0, 0);
}

struct KParams {
    const float *queries, *keys, *prior, *spk, *emo;
    const float *kw1, *kb1, *kw2, *kb2;
    const float *qw1, *qb1, *qw2, *qb2, *qw3, *qb3;
    const float *spk_kw, *spk_kb, *spk_qw, *spk_qb;
    const float *emo_kw, *emo_kb, *emo_qw, *emo_qb;
    const void* mask;
    float *q2, *kenc, *qenc;
    int* lens;
    unsigned short *Bt1, *Btq, *Abf1, *Abf2, *A1q, *A2q, *A3q;
    float *pqb1, *pqb2;
    float *out_attn, *out_lp;
};

// K1 partition: [0..1023] grid-strided zero+casts | [1024..1407] im2col | [1408] lens
#define PW_TOTAL (1024*1536 + 128*1024 + 256*256 + 128*256 + 128*128 + 256 + 128)
#define ZITEMS   (NB * NATT * NT2 / 4)     // 40960 f32x4
#define CAST_B   1024
#define K1_IM    CAST_B
#define K1_LENS  (K1_IM + 384)
#define K1_GRID  (K1_LENS + 1)

// ---------------------------------------------------------------------------
// K1: grid-strided {kenc zero, weight casts} | im2col with inline ILP-4 shifts
//     and coalesced ushort4 Bt writes | lens
__global__ __launch_bounds__(256)
void prep_im2col(KParams p) {
    __shared__ float xs[80 * 67];
    __shared__ float sh[80];
    int bx = blockIdx.x, tid = threadIdx.x;
    int lane = tid & 63, wv = tid >> 6;

    if (bx < CAST_B) {
        const int n0c = 1024 * 1536, n1c = 128 * 1024, n2c = 256 * 256,
                  n3c = 128 * 256, n4c = 128 * 128;
        const int TOT = ZITEMS + PW_TOTAL;
        for (int ii = bx * 256 + tid; ii < TOT; ii += CAST_B * 256) {
            int i = ii;
            if (i < ZITEMS) { f32x4 z = {}; ((f32x4*)p.kenc)[i] = z; continue; }
            i -= ZITEMS;
            if (i < n0c) { p.Abf1[i] = f2bf(p.kw1[i]); continue; }
            i -= n0c;
            if (i < n1c) { int oc = i >> 10;
                p.Abf2[i] = (oc < 80) ? f2bf(p.kw2[i]) : (unsigned short)0; continue; }
            i -= n1c;
            if (i < n2c) { int m = i >> 8, c = i & 255;
                p.A1q[i] = (m < 160 && c < 240) ? f2bf(p.qw1[m * 240 + c]) : (unsigned short)0; continue; }
            i -= n2c;
            if (i < n3c) { int m = i >> 8, c = i & 255;
                p.A2q[i] = (m < 80 && c < 160) ? f2bf(p.qw2[m * 160 + c]) : (unsigned short)0; continue; }
            i -= n3c;
            if (i < n4c) { int m = i >> 7, c = i & 127;
                p.A3q[i] = (m < 80 && c < 80) ? f2bf(p.qw3[m * 80 + c]) : (unsigned short)0; continue; }
            i -= n4c;
            if (i < 256) { p.pqb1[i] = (i < 160) ? p.qb1[i] : 0.f; continue; }
            i -= 256;
            p.pqb2[i] = (i < 80) ? p.qb2[i] : 0.f;
        }
        return;
    }
    if (bx < K1_LENS) {
        int u = bx - K1_IM;
        if (u < 256) {
            // ---- keys im2col, shifts recomputed with ILP-4 ----
            int x = u & 3, b = (u >> 2) & 7, z = u >> 5;
            int t0 = x * 64, ci0 = z * 64;
            const float* e1 = p.spk + (size_t)b * NTXT;
            const float* e2 = p.emo + (size_t)b * NTXT;
            #pragma unroll
            for (int g = 0; g < 4; ++g) {
                int cl = wv * 16 + g * 4;
                const float* w1b = p.spk_kw + (size_t)(ci0 + cl) * NTXT;
                const float* w2b = p.emo_kw + (size_t)(ci0 + cl) * NTXT;
                float s0 = 0.f, s1 = 0.f, s2 = 0.f, s3 = 0.f;
                #pragma unroll
                for (int st = 0; st < 8; ++st) {
                    int j = st * 64 + lane;
                    float ev1 = e1[j], ev2 = e2[j];
                    s0 += ev1 * w1b[j]            + ev2 * w2b[j];
                    s1 += ev1 * w1b[j + NTXT]     + ev2 * w2b[j + NTXT];
                    s2 += ev1 * w1b[j + 2 * NTXT] + ev2 * w2b[j + 2 * NTXT];
                    s3 += ev1 * w1b[j + 3 * NTXT] + ev2 * w2b[j + 3 * NTXT];
                }
                #pragma unroll
                for (int off = 32; off > 0; off >>= 1) {
                    s0 += __shfl_down(s0, off); s1 += __shfl_down(s1, off);
                    s2 += __shfl_down(s2, off); s3 += __shfl_down(s3, off);
                }
                if (lane == 0) {
                    int c = ci0 + cl;
                    sh[cl]     = s0 + p.spk_kb[c]     + p.emo_kb[c];
                    sh[cl + 1] = s1 + p.spk_kb[c + 1] + p.emo_kb[c + 1];
                    sh[cl + 2] = s2 + p.spk_kb[c + 2] + p.emo_kb[c + 2];
                    sh[cl + 3] = s3 + p.spk_kb[c + 3] + p.emo_kb[c + 3];
                }
            }
            __syncthreads();
            for (int i = tid; i < 64 * 66; i += 256) {
                int cis = i / 66, tt = i % 66;
                int tg = t0 + tt - 1;
                float v = 0.f;
                if (tg >= 0 && tg < NT2)
                    v = p.keys[((size_t)(b * NTXT + ci0 + cis)) * NT2 + tg] + sh[cis];
                xs[cis * 67 + tt] = v;
            }
            __syncthreads();
            for (int i = tid; i < 64 * 48; i += 256) {
                int t = i / 48, m = i - t * 48;
                int e0 = m * 4;
                unsigned short pk[4];
                #pragma unroll
                for (int jj = 0; jj < 4; ++jj) {
                    int e = e0 + jj;
                    int cis = e / 3, k = e - cis * 3;
                    pk[jj] = f2bf(xs[cis * 67 + t + k]);
                }
                *(ushort4*)(p.Bt1 + ((size_t)(b * NT2 + t0 + t)) * 1536 + (size_t)ci0 * 3 + e0) =
                    make_ushort4(pk[0], pk[1], pk[2], pk[3]);
            }
            return;
        }
        // ---- queries im2col, shifts recomputed with ILP-4 ----
        int qb = u - 256;
        int x = qb & 15, b = qb >> 4;
        int t0 = x * 64;
        const float* e1 = p.spk + (size_t)b * NTXT;
        const float* e2 = p.emo + (size_t)b * NTXT;
        #pragma unroll
        for (int g = 0; g < 5; ++g) {
            int cl = wv * 20 + g * 4;
            const float* w1b = p.spk_qw + (size_t)cl * NTXT;
            const float* w2b = p.emo_qw + (size_t)cl * NTXT;
            float s0 = 0.f, s1 = 0.f, s2 = 0.f, s3 = 0.f;
            #pragma unroll
            for (int st = 0; st < 8; ++st) {
                int j = st * 64 + lane;
                float ev1 = e1[j], ev2 = e2[j];
                s0 += ev1 * w1b[j]            + ev2 * w2b[j];
                s1 += ev1 * w1b[j + NTXT]     + ev2 * w2b[j + NTXT];
                s2 += ev1 * w1b[j + 2 * NTXT] + ev2 * w2b[j + 2 * NTXT];
                s3 += ev1 * w1b[j + 3 * NTXT] + ev2 * w2b[j + 3 * NTXT];
            }
            #pragma unroll
            for (int off = 32; off > 0; off >>= 1) {
                s0 += __shfl_down(s0, off); s1 += __shfl_down(s1, off);
                s2 += __shfl_down(s2, off); s3 += __shfl_down(s3, off);
            }
            if (lane == 0) {
                sh[cl]     = s0 + p.spk_qb[cl]     + p.emo_qb[cl];
                sh[cl + 1] = s1 + p.spk_qb[cl + 1] + p.emo_qb[cl + 1];
                sh[cl + 2] = s2 + p.spk_qb[cl + 2] + p.emo_qb[cl + 2];
                sh[cl + 3] = s3 + p.spk_qb[cl + 3] + p.emo_qb[cl + 3];
            }
        }
        __syncthreads();
        for (int i = tid; i < 80 * 66; i += 256) {
            int cis = i / 66, tt = i % 66;
            int tg = t0 + tt - 1;
            float v = 0.f;
            if (tg >= 0 && tg < NT1)
                v = p.queries[((size_t)(b * NMEL + cis)) * NT1 + tg] + sh[cis];
            xs[cis * 67 + tt] = v;
        }
        __syncthreads();
        for (int i = tid; i < 64 * 64; i += 256) {
            int t = i >> 6, m = i & 63;
            int tg = t0 + t;
            if (tg >= NT1) continue;
            int e0 = m * 4;
            unsigned short pk[4];
            #pragma unroll
            for (int jj = 0; jj < 4; ++jj) {
                int e = e0 + jj;
                unsigned short v = 0;
                if (e < 240) { int cis = e / 3, k = e - cis * 3; v = f2bf(xs[cis * 67 + t + k]); }
                pk[jj] = v;
            }
            *(ushort4*)(p.Btq + ((size_t)(b * NT1 + tg)) * 256 + e0) =
                make_ushort4(pk[0], pk[1], pk[2], pk[3]);
        }
        return;
    }
    // lens: one block, first wave
    if (tid >= 64) return;
    {
        const int* mi = (const int*)p.mask;
        int bf16p = 0, f16p = 0, f32m = 0, big = 0, one = 0;
        for (int i = tid; i < 512; i += 64) {
            unsigned v = (unsigned)mi[i];
            bf16p |= (v == 0x3F803F80u);
            f16p  |= (v == 0x3C003C00u) || (v == 0x3C000000u);
            f32m  |= (v == 0x3F800000u);
            big   |= (v > 1u);
            one   |= (v == 1u);
        }
        bf16p = __any(bf16p); f16p = __any(f16p); f32m = __any(f32m);
        big = __any(big); one = __any(one);
        int mode;
        if (bf16p)      mode = 3;
        else if (f16p)  mode = 4;
        else if (f32m)  mode = 2;
        else if (big)   mode = 0;
        else if (one)   mode = 1;
        else            mode = 5;
        for (int b = 0; b < NB; ++b) {
            int cnt = 0;
            for (int t = tid; t < NT2; t += 64) {
                bool m;
                switch (mode) {
                    case 0: m = ((const unsigned char*)p.mask)[b*NT2 + t] != 0; break;
                    case 1: m = ((const int*)p.mask)[b*NT2 + t] != 0; break;
                    case 2: m = ((const float*)p.mask)[b*NT2 + t] != 0.f; break;
                    case 3: case 4: m = ((const unsigned short*)p.mask)[b*NT2 + t] != 0; break;
                    default: m = false; break;
                }
                cnt += m ? 0 : 1;
            }
            for (int off = 32; off > 0; off >>= 1) cnt += __shfl_down(cnt, off);
            if (tid == 0) p.lens[b] = cnt;
        }
    }
}

// ---------------------------------------------------------------------------
// K2: blocks 0..255 keys conv1 (128x64, counted-vmcnt 2-phase pipeline) + mini
//     conv2 (atomicAdd); blocks 256..380 query chain (dbuf conv2/conv3 A).
__global__ __launch_bounds__(256)
void gemm_fused(KParams p) {
    __shared__ __attribute__((aligned(16))) char smem[74240];
    int tid = threadIdx.x, bx = blockIdx.x;
    int lane = tid & 63, wv = tid >> 6;
    int wr = wv >> 1, wc = wv & 1;
    int srow = lane >> 3;
    int selem = (((lane & 7) * 16) ^ ((srow & 7) << 4)) >> 1;

    if (bx < 256) {
        // XCD-locality remap: XCD j (bx%8) gets x in {4j..4j+3}, all 8 y.
        int j = bx & 7, i = bx >> 3;
        int x = j * 4 + (i & 3);
        int y = i >> 2;
        // layout: As0 [0,16K) As1 [16K,32K) Bs0 [32K,40K) Bs1 [40K,48K) B2c [48K,64K)
        unsigned short* B2c = (unsigned short*)(smem + 49152);
        int m0 = y * 128, n0 = x * 64;
        f32x4 acc[4][2] = {};

        {   // prologue: stage K-step 0 into buffer 0 (6 loads)
            #pragma unroll
            for (int i2 = 0; i2 < 4; ++i2) {
                int ch = wv * 4 + i2;
                gload_lds16(p.Abf1 + (size_t)(m0 + ch * 8 + srow) * 1536 + selem, smem + ch * 1024);
            }
            #pragma unroll
            for (int i2 = 0; i2 < 2; ++i2) {
                int ch = wv * 2 + i2;
                gload_lds16(p.Bt1 + (size_t)(n0 + ch * 8 + srow) * 1536 + selem, smem + 32768 + ch * 1024);
            }
        }
        int cur = 0;
        for (int t = 0; t < 24; ++t) {
            if (t < 23) {
                int k0n = (t + 1) * 64;
                char* an = smem + (cur ^ 1) * 16384;
                char* bn = smem + 32768 + (cur ^ 1) * 8192;
                #pragma unroll
                for (int i2 = 0; i2 < 4; ++i2) {
                    int ch = wv * 4 + i2;
                    gload_lds16(p.Abf1 + (size_t)(m0 + ch * 8 + srow) * 1536 + k0n + selem, an + ch * 1024);
                }
                #pragma unroll
                for (int i2 = 0; i2 < 2; ++i2) {
                    int ch = wv * 2 + i2;
                    gload_lds16(p.Bt1 + (size_t)(n0 + ch * 8 + srow) * 1536 + k0n + selem, bn + ch * 1024);
                }
                // wait ONLY for STAGE(t): the 6 loads just issued stay in flight
                asm volatile("s_waitcnt vmcnt(6)" ::: "memory");
            } else {
                asm volatile("s_waitcnt vmcnt(0)" ::: "memory");
            }
            __builtin_amdgcn_s_barrier();      // all waves' STAGE(t) visible
            const char* Ab = smem + cur * 16384;
            const char* Bb = smem + 32768 + cur * 8192;
            #pragma unroll
            for (int ks = 0; ks < 2; ++ks) {
                bf16x8 af[4], bfr[2];
                int kb = ks * 64 + (lane >> 4) * 16;
                #pragma unroll
                for (int mi = 0; mi < 4; ++mi) {
                    int row = wr * 64 + mi * 16 + (lane & 15);
                    af[mi] = *(const bf16x8*)(Ab + row * 128 + (kb ^ ((row & 7) << 4)));
                }
                #pragma unroll
                for (int ni = 0; ni < 2; ++ni) {
                    int row = wc * 32 + ni * 16 + (lane & 15);
                    bfr[ni] = *(const bf16x8*)(Bb + row * 128 + (kb ^ ((row & 7) << 4)));
                }
                #pragma unroll
                for (int mi = 0; mi < 4; ++mi)
                    #pragma unroll
                    for (int ni = 0; ni < 2; ++ni)
                        acc[mi][ni] = __builtin_amdgcn_mfma_f32_16x16x32_bf16(af[mi], bfr[ni], acc[mi][ni], 0, 0, 0);
            }
            __builtin_amdgcn_s_barrier();      // reads of cur done before overwrite
            cur ^= 1;
        }
        // epilogue: relu(acc+kb1) -> bf16 LDS B2c [col][local_ch 0..127], swizzled
        #pragma unroll
        for (int mi = 0; mi < 4; ++mi) {
            #pragma unroll
            for (int ni = 0; ni < 2; ++ni) {
                int mb = wr * 64 + mi * 16 + (lane >> 4) * 4;
                int row = wc * 32 + ni * 16 + (lane & 15);
                unsigned short pk[4];
                #pragma unroll
                for (int jj = 0; jj < 4; ++jj) {
                    float v = acc[mi][ni][jj] + p.kb1[m0 + mb + jj];
                    pk[jj] = f2bf(fmaxf(v, 0.f));
                }
                int bo = mb * 2;
                int addr = row * 256 + ((bo & ~15) ^ ((row & 7) << 4)) + (bo & 15);
                *(ushort4*)((char*)B2c + addr) = make_ushort4(pk[0], pk[1], pk[2], pk[3]);
            }
        }
        // mini conv2 (2-deep A prefetch)
        #pragma unroll
        for (int i2 = 0; i2 < 4; ++i2) {
            int ch = wv * 4 + i2;
            gload_lds16(p.Abf2 + (size_t)(ch * 8 + srow) * 1024 + y * 128 + selem, smem + ch * 1024);
        }
        __syncthreads();   // A2(k0=0) loaded AND B2c writes complete
        #pragma unroll
        for (int i2 = 0; i2 < 4; ++i2) {
            int ch = wv * 4 + i2;
            gload_lds16(p.Abf2 + (size_t)(ch * 8 + srow) * 1024 + y * 128 + 64 + selem, smem + 16384 + ch * 1024);
        }
        f32x4 acc2[4][2] = {};
        #pragma unroll
        for (int k0 = 0; k0 < 128; k0 += 64) {
            const char* Ab = smem + (k0 >> 6) * 16384;
            #pragma unroll
            for (int ks = 0; ks < 2; ++ks) {
                bf16x8 af[4], bfr[2];
                int kb = ks * 64 + (lane >> 4) * 16;
                #pragma unroll
                for (int mi = 0; mi < 4; ++mi) {
                    int row = wr * 64 + mi * 16 + (lane & 15);
                    af[mi] = *(const bf16x8*)(Ab + row * 128 + (kb ^ ((row & 7) << 4)));
                }
                #pragma unroll
                for (int ni = 0; ni < 2; ++ni) {
                    int row = wc * 32 + ni * 16 + (lane & 15);
                    int kbyte = k0 * 2 + kb;
                    bfr[ni] = *(const bf16x8*)((const char*)B2c + row * 256 + (kbyte ^ ((row & 7) << 4)));
                }
                #pragma unroll
                for (int mi = 0; mi < 4; ++mi)
                    #pragma unroll
                    for (int ni = 0; ni < 2; ++ni)
                        acc2[mi][ni] = __builtin_amdgcn_mfma_f32_16x16x32_bf16(af[mi], bfr[ni], acc2[mi][ni], 0, 0, 0);
            }
            if (k0 == 0) __syncthreads();
        }
        #pragma unroll
        for (int mi = 0; mi < 4; ++mi) {
            #pragma unroll
            for (int ni = 0; ni < 2; ++ni) {
                int mb = wr * 64 + mi * 16 + (lane >> 4) * 4;
                int n  = n0 + wc * 32 + ni * 16 + (lane & 15);
                int b = n >> 8, t = n & 255;
                #pragma unroll
                for (int jj = 0; jj < 4; ++jj) {
                    int m = mb + jj;
                    if (m < NATT) {
                        float v = acc2[mi][ni][jj] + ((y == 0) ? p.kb2[m] : 0.f);
                        atomicAdd(&p.kenc[((size_t)(b * NATT + m)) * NT2 + t], v);
                    }
                }
            }
        }
    } else {
        // ---- fused query chain ----
        unsigned short* As = (unsigned short*)smem;            // [128][64]
        unsigned short* Bs = (unsigned short*)(smem + 16384);  // [64][64]
        unsigned short* B2 = (unsigned short*)(smem + 24576);  // [64][256]
        unsigned short* B3 = (unsigned short*)(smem + 57344);  // [64][128]
        float* red = (float*)(smem + 73728);                   // [128]
        int n0 = (bx - 256) * 64;
        // conv1 (M=256 in 2 chunks, K=256), B from global Btq
        #pragma unroll
        for (int mc = 0; mc < 2; ++mc) {
            int m0 = mc * 128;
            f32x4 acc[4][2] = {};
            for (int k0 = 0; k0 < 256; k0 += 64) {
                #pragma unroll
                for (int i2 = 0; i2 < 4; ++i2) {
                    int ch = wv * 4 + i2;
                    gload_lds16(p.A1q + (size_t)(m0 + ch * 8 + srow) * 256 + k0 + selem, (char*)As + ch * 1024);
                }
                #pragma unroll
                for (int i2 = 0; i2 < 2; ++i2) {
                    int ch = wv * 2 + i2;
                    gload_lds16(p.Btq + (size_t)(n0 + ch * 8 + srow) * 256 + k0 + selem, (char*)Bs + ch * 1024);
                }
                __syncthreads();
                #pragma unroll
                for (int ks = 0; ks < 2; ++ks) {
                    bf16x8 af[4], bfr[2];
                    int kb = ks * 64 + (lane >> 4) * 16;
                    #pragma unroll
                    for (int mi = 0; mi < 4; ++mi) {
                        int row = wr * 64 + mi * 16 + (lane & 15);
                        af[mi] = *(const bf16x8*)((const char*)As + row * 128 + (kb ^ ((row & 7) << 4)));
                    }
                    #pragma unroll
                    for (int ni = 0; ni < 2; ++ni) {
                        int row = wc * 32 + ni * 16 + (lane & 15);
                        bfr[ni] = *(const bf16x8*)((const char*)Bs + row * 128 + (kb ^ ((row & 7) << 4)));
                    }
                    #pragma unroll
                    for (int mi = 0; mi < 4; ++mi)
                        #pragma unroll
                        for (int ni = 0; ni < 2; ++ni)
                            acc[mi][ni] = __builtin_amdgcn_mfma_f32_16x16x32_bf16(af[mi], bfr[ni], acc[mi][ni], 0, 0, 0);
                }
                __syncthreads();
            }
            #pragma unroll
            for (int mi = 0; mi < 4; ++mi) {
                #pragma unroll
                for (int ni = 0; ni < 2; ++ni) {
                    int mb = m0 + wr * 64 + mi * 16 + (lane >> 4) * 4;
                    int row = wc * 32 + ni * 16 + (lane & 15);
                    unsigned short pk[4];
                    #pragma unroll
                    for (int jj = 0; jj < 4; ++jj) {
                        float v = acc[mi][ni][jj] + p.pqb1[mb + jj];
                        pk[jj] = f2bf(fmaxf(v, 0.f));
                    }
                    int bo = mb * 2;
                    int addr = row * 512 + ((bo & ~15) ^ ((row & 7) << 4)) + (bo & 15);
                    *(ushort4*)((char*)B2 + addr) = make_ushort4(pk[0], pk[1], pk[2], pk[3]);
                }
            }
        }
        // conv2 (M=128, K=256), B in LDS B2; A double-buffered (As0 @0, As1 @B3 region)
        {
            char* Abuf[2] = { smem, smem + 57344 };
            #pragma unroll
            for (int i2 = 0; i2 < 4; ++i2) {
                int ch = wv * 4 + i2;
                gload_lds16(p.A2q + (size_t)(ch * 8 + srow) * 256 + selem, Abuf[0] + ch * 1024);
            }
            __syncthreads();   // As0 ready AND B2 writes complete
            f32x4 acc[4][2] = {};
            for (int t = 0; t < 4; ++t) {
                if (t < 3) {
                    int k0n = (t + 1) * 64;
                    char* an = Abuf[(t + 1) & 1];
                    #pragma unroll
                    for (int i2 = 0; i2 < 4; ++i2) {
                        int ch = wv * 4 + i2;
                        gload_lds16(p.A2q + (size_t)(ch * 8 + srow) * 256 + k0n + selem, an + ch * 1024);
                    }
                }
                const char* Ab = Abuf[t & 1];
                int k0 = t * 64;
                #pragma unroll
                for (int ks = 0; ks < 2; ++ks) {
                    bf16x8 af[4], bfr[2];
                    int kb = ks * 64 + (lane >> 4) * 16;
                    #pragma unroll
                    for (int mi = 0; mi < 4; ++mi) {
                        int row = wr * 64 + mi * 16 + (lane & 15);
                        af[mi] = *(const bf16x8*)(Ab + row * 128 + (kb ^ ((row & 7) << 4)));
                    }
                    #pragma unroll
                    for (int ni = 0; ni < 2; ++ni) {
                        int row = wc * 32 + ni * 16 + (lane & 15);
                        int kbyte = k0 * 2 + kb;
                        bfr[ni] = *(const bf16x8*)((const char*)B2 + row * 512 + (kbyte ^ ((row & 7) << 4)));
                    }
                    #pragma unroll
                    for (int mi = 0; mi < 4; ++mi)
                        #pragma unroll
                        for (int ni = 0; ni < 2; ++ni)
                            acc[mi][ni] = __builtin_amdgcn_mfma_f32_16x16x32_bf16(af[mi], bfr[ni], acc[mi][ni], 0, 0, 0);
                }
                __syncthreads();
            }
            #pragma unroll
            for (int mi = 0; mi < 4; ++mi) {
                #pragma unroll
                for (int ni = 0; ni < 2; ++ni) {
                    int mb = wr * 64 + mi * 16 + (lane >> 4) * 4;
                    int row = wc * 32 + ni * 16 + (lane & 15);
                    unsigned short pk[4];
                    #pragma unroll
                    for (int jj = 0; jj < 4; ++jj) {
                        float v = acc[mi][ni][jj] + p.pqb2[mb + jj];
                        pk[jj] = f2bf(fmaxf(v, 0.f));
                    }
                    int bo = mb * 2;
                    int addr = row * 256 + ((bo & ~15) ^ ((row & 7) << 4)) + (bo & 15);
                    *(ushort4*)((char*)B3 + addr) = make_ushort4(pk[0], pk[1], pk[2], pk[3]);
                }
            }
        }
        // conv3 (M=128, K=128), B in LDS B3; A dbuf (As0 @0, As1 @B2 region)
        {
            #pragma unroll
            for (int i2 = 0; i2 < 4; ++i2) {
                int ch = wv * 4 + i2;
                gload_lds16(p.A3q + (size_t)(ch * 8 + srow) * 128 + selem, smem + ch * 1024);
                gload_lds16(p.A3q + (size_t)(ch * 8 + srow) * 128 + 64 + selem, smem + 24576 + ch * 1024);
            }
            __syncthreads();   // both A stages ready AND B3 writes complete
            f32x4 acc[4][2] = {};
            #pragma unroll
            for (int k0 = 0; k0 < 128; k0 += 64) {
                const char* Ab = (k0 == 0) ? smem : smem + 24576;
                #pragma unroll
                for (int ks = 0; ks < 2; ++ks) {
                    bf16x8 af[4], bfr[2];
                    int kb = ks * 64 + (lane >> 4) * 16;
                    #pragma unroll
                    for (int mi = 0; mi < 4; ++mi) {
                        int row = wr * 64 + mi * 16 + (lane & 15);
                        af[mi] = *(const bf16x8*)(Ab + row * 128 + (kb ^ ((row & 7) << 4)));
                    }
                    #pragma unroll
                    for (int ni = 0; ni < 2; ++ni) {
                        int row = wc * 32 + ni * 16 + (lane & 15);
                        int kbyte = k0 * 2 + kb;
                        bfr[ni] = *(const bf16x8*)((const char*)B3 + row * 256 + (kbyte ^ ((row & 7) << 4)));
                    }
                    #pragma unroll
                    for (int mi = 0; mi < 4; ++mi)
                        #pragma unroll
                        for (int ni = 0; ni < 2; ++ni)
                            acc[mi][ni] = __builtin_amdgcn_mfma_f32_16x16x32_bf16(af[mi], bfr[ni], acc[mi][ni], 0, 0, 0);
                }
            }
            float part[2] = {0.f, 0.f};
            #pragma unroll
            for (int mi = 0; mi < 4; ++mi) {
                #pragma unroll
                for (int ni = 0; ni < 2; ++ni) {
                    int mb = wr * 64 + mi * 16 + (lane >> 4) * 4;
                    int n  = n0 + wc * 32 + ni * 16 + (lane & 15);
                    int b = n / NT1, t = n - b * NT1;
                    #pragma unroll
                    for (int jj = 0; jj < 4; ++jj) {
                        int m = mb + jj;
                        if (m < NATT) {
                            float v = acc[mi][ni][jj] + p.qb3[m];
                            part[ni] += v * v;
                            p.qenc[((size_t)(b * NATT + m)) * NT1 + t] = v;
                        }
                    }
                }
            }
            #pragma unroll
            for (int ni = 0; ni < 2; ++ni) {
                part[ni] += __shfl_xor(part[ni], 16);
                part[ni] += __shfl_xor(part[ni], 32);
            }
            if ((lane >> 4) == 0) {
                red[wr * 64 + wc * 32 + (lane & 15)]      = part[0];
                red[wr * 64 + wc * 32 + 16 + (lane & 15)] = part[1];
            }
            __syncthreads();
            if (tid < 64) p.q2[n0 + tid] = red[tid] + red[64 + tid];
        }
    }
}

// ---------------------------------------------------------------------------
// K3: attn, t-tile 16 (4 rows/wave), grid 504 = 63 tiles x 8 b. k2 inline.
__global__ __launch_bounds__(256)
void attn_kernel(KParams p) {
    __shared__ float kl[16 * 256];
    __shared__ float ql[16 * 16];
    int bx = blockIdx.x, tid = threadIdx.x;
    int lane = tid & 63, wv = tid >> 6;
    int b = bx / 63;
    int t0 = (bx - b * 63) * 16;
    int s0 = lane * 4;
    f32x4 acc[4] = {};
    f32x4 k2v = {};
    for (int ci0 = 0; ci0 < NATT; ci0 += 16) {
        for (int i = tid; i < 1024; i += 256) {
            int ci = i >> 6, sq = (i & 63) * 4;
            *(f32x4*)&kl[ci * 256 + sq] =
                *(const f32x4*)&p.kenc[((size_t)(b * NATT + ci0 + ci)) * NT2 + sq];
        }
        {
            int ci = tid >> 4, tt = tid & 15;
            int tg = t0 + tt;
            ql[ci * 16 + tt] = (tg < NT1) ? p.qenc[((size_t)(b * NATT + ci0 + ci)) * NT1 + tg] : 0.f;
        }
        __syncthreads();
        #pragma unroll
        for (int ci = 0; ci < 16; ++ci) {
            f32x4 kv = *(const f32x4*)&kl[ci * 256 + s0];
            #pragma unroll
            for (int jj = 0; jj < 4; ++jj) k2v[jj] += kv[jj] * kv[jj];
            f32x4 qa = *(const f32x4*)&ql[ci * 16 + wv * 4];
            #pragma unroll
            for (int r = 0; r < 4; ++r)
                #pragma unroll
                for (int jj = 0; jj < 4; ++jj) acc[r][jj] += qa[r] * kv[jj];
        }
        __syncthreads();
    }
    int len = p.lens[b];
    #pragma unroll
    for (int r = 0; r < 4; ++r) {
        int t = t0 + wv * 4 + r;
        if (t >= NT1) continue;
        float q2v = p.q2[b * NT1 + t];
        float lg[4];
        float mx = -INFINITY;
        #pragma unroll
        for (int jj = 0; jj < 4; ++jj) {
            lg[jj] = -FTEMP * (q2v + k2v[jj] - 2.f * acc[r][jj]);
            mx = fmaxf(mx, lg[jj]);
        }
        for (int off = 32; off > 0; off >>= 1) mx = fmaxf(mx, __shfl_xor(mx, off));
        float se = 0.f;
        #pragma unroll
        for (int jj = 0; jj < 4; ++jj) se += __expf(lg[jj] - mx);
        for (int off = 32; off > 0; off >>= 1) se += __shfl_xor(se, off);
        float logZ = mx + __logf(se);
        f32x4 prv = *(const f32x4*)&p.prior[((size_t)b * NT1 + t) * NT2 + s0];
        float lp[4];
        float mx2 = -INFINITY;
        #pragma unroll
        for (int jj = 0; jj < 4; ++jj) {
            lp[jj] = lg[jj] - logZ + __logf(prv[jj] + 1e-8f);
            if (s0 + jj < len) mx2 = fmaxf(mx2, lp[jj]);
        }
        for (int off = 32; off > 0; off >>= 1) mx2 = fmaxf(mx2, __shfl_xor(mx2, off));
        float se2 = 0.f;
        float ex[4];
        #pragma unroll
        for (int jj = 0; jj < 4; ++jj) {
            ex[jj] = (s0 + jj < len) ? __expf(lp[jj] - mx2) : 0.f;
            se2 += ex[jj];
        }
        for (int off = 32; off > 0; off >>= 1) se2 += __shfl_xor(se2, off);
        float inv = 1.f / se2;
        size_t o = ((size_t)b * NT1 + t) * NT2 + s0;
        f32x4 oa, ol;
        #pragma unroll
        for (int jj = 0; jj < 4; ++jj) { oa[jj] = ex[jj] * inv; ol[jj] = lp[jj]; }
        *(f32x4*)&p.out_attn[o] = oa;
        *(f32x4*)&p.out_lp[o]   = ol;
    }
}

// ---------------------------------------------------------------------------
extern "C" void kernel_launch(void* const* d_in, const int* in_sizes, int n_in,
                              void* d_out, int out_size, void* d_ws, size_t ws_size,
                              hipStream_t stream) {
    (void)in_sizes; (void)n_in; (void)out_size; (void)ws_size;
    KParams p;
    p.queries = (const float*)d_in[0];
    p.keys    = (const float*)d_in[1];
    p.prior   = (const float*)d_in[2];
    p.spk     = (const float*)d_in[3];
    p.emo     = (const float*)d_in[4];
    p.kw1     = (const float*)d_in[5];
    p.kb1     = (const float*)d_in[6];
    p.kw2     = (const float*)d_in[7];
    p.kb2     = (const float*)d_in[8];
    p.qw1     = (const float*)d_in[9];
    p.qb1     = (const float*)d_in[10];
    p.qw2     = (const float*)d_in[11];
    p.qb2     = (const float*)d_in[12];
    p.qw3     = (const float*)d_in[13];
    p.qb3     = (const float*)d_in[14];
    p.spk_kw  = (const float*)d_in[15];
    p.spk_kb  = (const float*)d_in[16];
    p.spk_qw  = (const float*)d_in[17];
    p.spk_qb  = (const float*)d_in[18];
    p.emo_kw  = (const float*)d_in[19];
    p.emo_kb  = (const float*)d_in[20];
    p.emo_qw  = (const float*)d_in[21];
    p.emo_qb  = (const float*)d_in[22];
    p.mask    = d_in[23];

    float* w = (float*)d_ws;
    size_t off = 0;
    p.lens   = (int*)(w + off); off += 16;
    p.q2     = w + off; off += NB * NT1;
    p.kenc   = w + off; off += (size_t)NB * NATT * NT2;
    p.qenc   = w + off; off += (size_t)NB * NATT * NT1;
    p.Bt1    = (unsigned short*)(w + off); off += (size_t)2048 * 1536 / 2;
    p.Btq    = (unsigned short*)(w + off); off += (size_t)8064 * 256 / 2;
    p.Abf1   = (unsigned short*)(w + off); off += (size_t)1024 * 1536 / 2;
    p.Abf2   = (unsigned short*)(w + off); off += (size_t)128 * 1024 / 2;
    p.A1q    = (unsigned short*)(w + off); off += (size_t)256 * 256 / 2;
    p.A2q    = (unsigned short*)(w + off); off += (size_t)128 * 256 / 2;
    p.A3q    = (unsigned short*)(w + off); off += (size_t)128 * 128 / 2;
    p.pqb1   = w + off; off += 256;
    p.pqb2   = w + off; off += 128;

    p.out_attn = (float*)d_out;
    p.out_lp   = p.out_attn + (size_t)NB * NT1 * NT2;

    prep_im2col<<<K1_GRID, 256, 0, stream>>>(p);
    gemm_fused<<<381, 256, 0, stream>>>(p);
    attn_kernel<<<504, 256, 0, stream>>>(p);
}